// Round 1
// baseline (188.563 us; speedup 1.0000x reference)
//
#include <hip/hip_runtime.h>

// VQ-VAE vector quantization forward — MFMA fast-path + exact np recheck.
// x: [32,64,64,64] f32 -> flat [N=131072, D=64]; embeddings: [D=64, K=512].
//
// Exactness contract (validated rounds 2-9 at absmax 0.0): chosen index per
// row == np argmin over dist_k = fl(fl(A+B_k) - fl(2*sim_k)), first-min tie;
// A = np pairwise 8-acc sum(f*f); B_k = sequential sum(e*e); sim = sequential
// FMA chain over d. out = fl(x + fl(q-x)); loss = 1.25*mean((q-x)^2).
//
// Round 11 — attack the two biggest dispatches the r10 counters exposed:
//  - vq_main (74us): latency-bound (MfmaUtil 18%, floors ~14us MFMA / ~15us
//    L2 table / ~10.6us HBM). Each wave re-loaded the same 4KB ebf tile from
//    L2 per t (512MB aggregate, 4x redundant per block). Now: double-buffered
//    LDS staging, reg-staged async split (issue 16B/thread global load of
//    tile t+1 -> MFMA phase hides L2 latency -> ds_write -> 1 barrier/t).
//    L2 table traffic /4; b-frags via conflict-free ds_read_b128. e2 staged
//    to LDS once. m2 update as min(max(s,m1),m2) (identical selection, fuses
//    to v_med3_f32). Numerics of the argmin/flag path bit-identical to r10.
//  - vq_fix (77us worst, ~0% VALU): one wave per flagged row streamed the
//    full 128KB emb from L2 per row (~GBs, no reuse). Now 8 rows/wave: each
//    2KB ev load feeds 64 FMAs; grid 512 blocks. np-exact chains verbatim.
// vq_prep / finalize / margin logic / layouts: byte-identical to r10.

constexpr int D = 64;
constexpr int K = 512;
constexpr int NROWS = 131072;
constexpr long long NELEM = 8388608LL;
constexpr int RPB = 128;     // rows per block (2 row-tiles per wave)
constexpr float THRESH = 1e-3f;
constexpr int SLOWCAP = 16384;

typedef __attribute__((ext_vector_type(8))) short bf16x8;
typedef __attribute__((ext_vector_type(4))) float f32x4;

__device__ __forceinline__ unsigned short bf16_rne(float f) {
    unsigned int u = __float_as_uint(f);
    unsigned int r = u + 0x7fffu + ((u >> 16) & 1u);
    return (unsigned short)(r >> 16);
}
__device__ __forceinline__ float bf16_f(unsigned short h) {
    return __uint_as_float(((unsigned int)h) << 16);
}

// ws map (float offsets): 0 loss | 1 cnt | 64 e2[512] | 1024 ebf (128KB)
// | 33792 embT[512*64] | 66560 slow[16384] ints.

// Prep: 8 blocks x 256. Block b owns codes [b*64, b*64+64).
__global__ __launch_bounds__(256) void vq_prep(const float* __restrict__ emb,
                                               float* __restrict__ e2,
                                               unsigned short* __restrict__ ebf,
                                               float* __restrict__ embT,
                                               float* __restrict__ loss_acc,
                                               int* __restrict__ cnt) {
    const int tid = threadIdx.x;
    const int b = blockIdx.x;
    const int c0 = b * 64;
    __shared__ float se[64 * 65];  // se[d*65 + c_local]

    // Stage: 64 d x 64 codes, coalesced 256B segments (4 d's per iter).
    {
        const int wv = tid >> 6, cl = tid & 63;
#pragma unroll
        for (int it = 0; it < 16; ++it) {
            const int d = it * 4 + wv;
            se[d * 65 + cl] = emb[d * K + c0 + cl];
        }
    }
    __syncthreads();

    // e2: np axis-0 sequential order (identical rounding chain to r9).
    if (tid < 64) {
        const int cl = tid;
        float bacc = __fmul_rn(se[cl], se[cl]);
#pragma unroll
        for (int d = 1; d < 64; ++d) {
            float e = se[d * 65 + cl];
            bacc = __fadd_rn(bacc, __fmul_rn(e, e));
        }
        e2[c0 + cl] = bacc;
    }

    // embT[c][d]: dwordx4 coalesced writes (1024 float4 / 256 thr = 4 iters).
#pragma unroll
    for (int it = 0; it < 4; ++it) {
        const int idx = it * 256 + tid;     // float4 index in 64x64 tile
        const int cl = idx >> 4;
        const int d0 = (idx & 15) * 4;
        float4 v;
        v.x = se[(d0 + 0) * 65 + cl];
        v.y = se[(d0 + 1) * 65 + cl];
        v.z = se[(d0 + 2) * 65 + cl];
        v.w = se[(d0 + 3) * 65 + cl];
        *reinterpret_cast<float4*>(embT + (size_t)(c0 + cl) * D + d0) = v;
    }

    // ebf: block owns tiles t = b*4 .. b*4+3 (8192 shorts = 1024 uint4).
    // layout (r9-identical): tile*2048 + table*1024 + half*512 + lane*8 + j,
    // value = split_table( e[d = q*8+j+32*half][c = tile*16 + (lane&15)] ).
#pragma unroll
    for (int it = 0; it < 4; ++it) {
        const int w = it * 256 + tid;       // uint4 index within block's span
        const int tl = w >> 8;              // local tile 0..3
        const int rem = w & 255;
        const int table = rem >> 7;
        const int half = (rem >> 6) & 1;
        const int lane = rem & 63;
        const int q = lane >> 4, mm = lane & 15;
        const int cl = tl * 16 + mm;
        unsigned short v[8];
#pragma unroll
        for (int j = 0; j < 8; ++j) {
            const float e = se[(q * 8 + j + 32 * half) * 65 + cl];
            unsigned short h1 = bf16_rne(e);
            v[j] = table ? bf16_rne(e - bf16_f(h1)) : h1;
        }
        *reinterpret_cast<uint4*>(ebf + (size_t)(b * 4 + tl) * 2048 +
                                  table * 1024 + half * 512 + lane * 8) =
            *reinterpret_cast<const uint4*>(&v[0]);
    }

    if (b == 0 && tid == 0) { loss_acc[0] = 0.f; cnt[0] = 0; }
}

// Main: MFMA argmin, 2 row-tiles/wave, LDS-staged ebf tiles (dbuf) +
// fused epilogue + loss.
__global__ __launch_bounds__(256, 4) void vq_main(
    const float* __restrict__ x, const float* __restrict__ e2g,
    const unsigned short* __restrict__ ebf, const float* __restrict__ embT,
    float* __restrict__ out, float* __restrict__ loss_acc,
    int* __restrict__ slow, int* __restrict__ cnt) {
    const int tid = threadIdx.x;
    const int l = tid & 63;
    const int wv = tid >> 6;
    const int m = l & 15, q = l >> 4;

    __shared__ __align__(16) unsigned short sbf[2][2048];  // 2 x 4KB tile
    __shared__ float se2[512];
    __shared__ int bxl[RPB];
    __shared__ float wsum[4];

    // Prologue staging: tile 0 -> sbf[0], e2 -> se2 (latency hidden under
    // the A-fragment global loads + bf16 split below).
    {
        uint4 s0 = *reinterpret_cast<const uint4*>(ebf + tid * 8);
        *reinterpret_cast<uint4*>(&sbf[0][tid * 8]) = s0;
        if (tid < 128)
            reinterpret_cast<float4*>(se2)[tid] =
                reinterpret_cast<const float4*>(e2g)[tid];
    }

    // A-fragments for 2 row-tiles (rows wv*32 + rt*16 + m).
    bf16x8 a10[2], a11[2], a20[2], a21[2];
#pragma unroll
    for (int rt = 0; rt < 2; ++rt) {
        const float* xr =
            x + ((size_t)blockIdx.x * RPB + wv * 32 + rt * 16 + m) * D + q * 8;
        float4 v0 = *reinterpret_cast<const float4*>(xr);
        float4 v1 = *reinterpret_cast<const float4*>(xr + 4);
        float4 v2 = *reinterpret_cast<const float4*>(xr + 32);
        float4 v3 = *reinterpret_cast<const float4*>(xr + 36);
        float h0[8] = {v0.x, v0.y, v0.z, v0.w, v1.x, v1.y, v1.z, v1.w};
        float h1f[8] = {v2.x, v2.y, v2.z, v2.w, v3.x, v3.y, v3.z, v3.w};
        union { bf16x8 v; unsigned short u[8]; } u10, u11, u20, u21;
#pragma unroll
        for (int j = 0; j < 8; ++j) {
            unsigned short p = bf16_rne(h0[j]), r = bf16_rne(h1f[j]);
            u10.u[j] = p; u11.u[j] = r;
            u20.u[j] = bf16_rne(h0[j] - bf16_f(p));
            u21.u[j] = bf16_rne(h1f[j] - bf16_f(r));
        }
        a10[rt] = u10.v; a11[rt] = u11.v; a20[rt] = u20.v; a21[rt] = u21.v;
    }

    float m1[2][4], m2[2][4];
    int i1[2][4];
#pragma unroll
    for (int rt = 0; rt < 2; ++rt)
#pragma unroll
        for (int g = 0; g < 4; ++g) {
            m1[rt][g] = 3.0e38f; m2[rt][g] = 3.0e38f; i1[rt][g] = 0;
        }

    __syncthreads();  // tile 0 + se2 staged

#pragma unroll 2
    for (int t = 0; t < 32; ++t) {
        const int cur = t & 1;
        // Async-STAGE split: issue next tile's 16B/thread load NOW; its L2
        // latency hides under the ds_read+MFMA+update phase below.
        const int tn = (t + 1) & 31;  // t=31 wraps (harmless re-stage of 0)
        const uint4 stg =
            *reinterpret_cast<const uint4*>(ebf + tn * 2048 + tid * 8);

        // b-frags from LDS: contiguous ds_read_b128, conflict-free.
        const unsigned short* tb = &sbf[cur][l * 8];
        bf16x8 b10 = *reinterpret_cast<const bf16x8*>(tb);
        bf16x8 b11 = *reinterpret_cast<const bf16x8*>(tb + 512);
        bf16x8 b20 = *reinterpret_cast<const bf16x8*>(tb + 1024);
        bf16x8 b21 = *reinterpret_cast<const bf16x8*>(tb + 1536);
        const float Bn = se2[t * 16 + m];
        const int col = t * 16 + m;
        f32x4 cp[2], cq[2];
#pragma unroll
        for (int rt = 0; rt < 2; ++rt) {
            cp[rt] = f32x4{0.f, 0.f, 0.f, 0.f};
            cq[rt] = f32x4{0.f, 0.f, 0.f, 0.f};
        }
        // 16 MFMAs as 4 independent 4-chains (full split product).
#pragma unroll
        for (int rt = 0; rt < 2; ++rt) {
            cp[rt] = __builtin_amdgcn_mfma_f32_16x16x32_bf16(a10[rt], b10, cp[rt], 0, 0, 0);
            cq[rt] = __builtin_amdgcn_mfma_f32_16x16x32_bf16(a20[rt], b10, cq[rt], 0, 0, 0);
            cp[rt] = __builtin_amdgcn_mfma_f32_16x16x32_bf16(a11[rt], b11, cp[rt], 0, 0, 0);
            cq[rt] = __builtin_amdgcn_mfma_f32_16x16x32_bf16(a21[rt], b11, cq[rt], 0, 0, 0);
            cp[rt] = __builtin_amdgcn_mfma_f32_16x16x32_bf16(a20[rt], b20, cp[rt], 0, 0, 0);
            cq[rt] = __builtin_amdgcn_mfma_f32_16x16x32_bf16(a10[rt], b20, cq[rt], 0, 0, 0);
            cp[rt] = __builtin_amdgcn_mfma_f32_16x16x32_bf16(a21[rt], b21, cp[rt], 0, 0, 0);
            cq[rt] = __builtin_amdgcn_mfma_f32_16x16x32_bf16(a11[rt], b21, cq[rt], 0, 0, 0);
        }
#pragma unroll
        for (int rt = 0; rt < 2; ++rt)
#pragma unroll
            for (int g = 0; g < 4; ++g) {
                float s = fmaf(-2.f, cp[rt][g] + cq[rt][g], Bn);
                // m2' = med3(s, m1, m2) given m1<=m2 — identical selection to
                // the r10 cndmask chain, 2 ops (fuses to v_med3_f32).
                m2[rt][g] = fminf(fmaxf(s, m1[rt][g]), m2[rt][g]);
                bool lt1 = s < m1[rt][g];
                if (lt1) { m1[rt][g] = s; i1[rt][g] = col; }
            }
        // Write the staged tile (vmcnt wait lands here, after ~16 MFMAs),
        // then the single per-t barrier: next tile ready AND everyone done
        // reading sbf[cur] (ds_reads completed before their MFMAs).
        *reinterpret_cast<uint4*>(&sbf[cur ^ 1][tid * 8]) = stg;
        __syncthreads();
    }

    // Combine across the 16 lanes of each quad (validated rounds 7-9).
#pragma unroll
    for (int rt = 0; rt < 2; ++rt)
#pragma unroll
        for (int g = 0; g < 4; ++g) {
#pragma unroll
            for (int off = 1; off < 16; off <<= 1) {
                float o1 = __shfl_xor(m1[rt][g], off, 64);
                int oi = __shfl_xor(i1[rt][g], off, 64);
                float o2 = __shfl_xor(m2[rt][g], off, 64);
                float nm2 =
                    fminf(fmaxf(m1[rt][g], o1), fminf(m2[rt][g], o2));
                bool take = (o1 < m1[rt][g]) ||
                            (o1 == m1[rt][g] && oi < i1[rt][g]);
                if (take) { m1[rt][g] = o1; i1[rt][g] = oi; }
                m2[rt][g] = nm2;  // equal mins, diff idx -> gap 0 -> slow
            }
            if (m == 0) {
                const int rl = wv * 32 + rt * 16 + q * 4 + g;  // row in block
                bxl[rl] = i1[rt][g];
                if (!((m2[rt][g] - m1[rt][g]) > THRESH)) {
                    int p = atomicAdd(cnt, 1);
                    if (p < SLOWCAP)
                        slow[p] = ((blockIdx.x * RPB + rl) << 9) | i1[rt][g];
                }
            }
        }
    __syncthreads();

    // Fused epilogue (r6-validated numerics, embT contiguous gather).
    float lsum = 0.f;
#pragma unroll
    for (int j = 0; j < 8; ++j) {
        const int e4 = j * 256 + tid;
        const int rr2 = e4 >> 4;
        const int d0 = (e4 & 15) * 4;
        const size_t gbase = (size_t)(blockIdx.x * RPB + rr2) * D + d0;
        const float4 xv = *reinterpret_cast<const float4*>(x + gbase);
        const float4 qv =
            *reinterpret_cast<const float4*>(embT + bxl[rr2] * D + d0);
        float4 o;
        float t;
        t = __fsub_rn(qv.x, xv.x); lsum = __fmaf_rn(t, t, lsum);
        o.x = __fadd_rn(xv.x, t);
        t = __fsub_rn(qv.y, xv.y); lsum = __fmaf_rn(t, t, lsum);
        o.y = __fadd_rn(xv.y, t);
        t = __fsub_rn(qv.z, xv.z); lsum = __fmaf_rn(t, t, lsum);
        o.z = __fadd_rn(xv.z, t);
        t = __fsub_rn(qv.w, xv.w); lsum = __fmaf_rn(t, t, lsum);
        o.w = __fadd_rn(xv.w, t);
        *reinterpret_cast<float4*>(out + gbase) = o;
    }
#pragma unroll
    for (int off = 32; off > 0; off >>= 1) lsum += __shfl_down(lsum, off, 64);
    if (l == 0) wsum[wv] = lsum;
    __syncthreads();
    if (tid == 0)
        atomicAdd(loss_acc, wsum[0] + wsum[1] + wsum[2] + wsum[3]);
}

// Fix: exact np rescan of flagged rows. r11: 8 rows per wave so each 2KB
// emb row-slice load feeds 64 FMAs (8x amortization; r10 streamed 128KB of
// emb from L2 per row). All np-exact chains (A pairwise-8, sequential-d FMA,
// first-min tie, rewrite, loss delta) verbatim from r9/r10. Grid 512 blocks.
__global__ __launch_bounds__(256) void vq_fix(const float* __restrict__ x,
                                              const float* __restrict__ emb,
                                              const float* __restrict__ embT,
                                              const float* __restrict__ e2g,
                                              const int* __restrict__ slow,
                                              const int* __restrict__ cnt,
                                              float* __restrict__ out,
                                              float* __restrict__ loss_acc) {
    int n = cnt[0];
    if (n > SLOWCAP) n = SLOWCAP;
    const int lane = threadIdx.x & 63;
    const int wg = blockIdx.x * 4 + (threadIdx.x >> 6);  // 2048 waves
#pragma unroll 1
    for (int base = wg * 8; base < n; base += 2048 * 8) {
        const int c8 = (n - base < 8) ? (n - base) : 8;
        int rows[8], fidxs[8];
        float A[8];
        // Entry decode + np-exact A (pairwise 8-acc), uniform scalar chain.
#pragma unroll
        for (int j = 0; j < 8; ++j) {
            rows[j] = 0; fidxs[j] = 0; A[j] = 0.f;
            if (j < c8) {
                const int entry = __builtin_amdgcn_readfirstlane(slow[base + j]);
                rows[j] = entry >> 9;
                fidxs[j] = entry & 511;
                const float* fr = x + (size_t)rows[j] * D;
                float r8[8];
#pragma unroll
                for (int jj = 0; jj < 8; ++jj)
                    r8[jj] = __fmul_rn(fr[jj], fr[jj]);
#pragma unroll
                for (int ii = 8; ii < D; ii += 8)
#pragma unroll
                    for (int jj = 0; jj < 8; ++jj)
                        r8[jj] = __fadd_rn(r8[jj],
                                           __fmul_rn(fr[ii + jj], fr[ii + jj]));
                A[j] = __fadd_rn(
                    __fadd_rn(__fadd_rn(r8[0], r8[1]), __fadd_rn(r8[2], r8[3])),
                    __fadd_rn(__fadd_rn(r8[4], r8[5]), __fadd_rn(r8[6], r8[7])));
            }
        }
        // Shared sim phase: one emb row-slice load feeds all 8 rows.
        float acc[8][8];
#pragma unroll
        for (int j = 0; j < 8; ++j)
#pragma unroll
            for (int u = 0; u < 8; ++u) acc[j][u] = 0.f;
#pragma unroll 4
        for (int d = 0; d < D; ++d) {
            float ev[8];
#pragma unroll
            for (int u = 0; u < 8; ++u) ev[u] = emb[d * K + lane + 64 * u];
#pragma unroll
            for (int j = 0; j < 8; ++j)
                if (j < c8) {
                    const float xd = x[(size_t)rows[j] * D + d];  // scalar
#pragma unroll
                    for (int u = 0; u < 8; ++u)
                        acc[j][u] = __fmaf_rn(xd, ev[u], acc[j][u]);
                }
        }
        float e2v[8];
#pragma unroll
        for (int u = 0; u < 8; ++u) e2v[u] = e2g[lane + 64 * u];
        // Per-row argmin + rewrite + loss delta (r9-identical chains).
#pragma unroll
        for (int j = 0; j < 8; ++j)
            if (j < c8) {
                const int row = rows[j];
                const int fidx = fidxs[j];
                float bv = 3.0e38f;
                int bi = 0;
#pragma unroll
                for (int u = 0; u < 8; ++u) {
                    const int c = lane + 64 * u;
                    float dv = __fsub_rn(__fadd_rn(A[j], e2v[u]),
                                         __fmul_rn(2.f, acc[j][u]));
                    if (dv < bv) { bv = dv; bi = c; }  // ascending c in lane
                }
#pragma unroll
                for (int off = 1; off < 64; off <<= 1) {
                    float ov = __shfl_xor(bv, off, 64);
                    int oi = __shfl_xor(bi, off, 64);
                    if (ov < bv || (ov == bv && oi < bi)) { bv = ov; bi = oi; }
                }
                float part = 0.f;
                if (lane < 16) {
                    const int d0 = lane * 4;
                    const float4 xv = *reinterpret_cast<const float4*>(
                        x + (size_t)row * D + d0);
                    const float4 qo = *reinterpret_cast<const float4*>(
                        embT + fidx * D + d0);
                    const float4 qn = *reinterpret_cast<const float4*>(
                        embT + bi * D + d0);
                    float so = 0.f, sn = 0.f, t;
                    float4 o;
                    t = __fsub_rn(qo.x, xv.x); so = __fmaf_rn(t, t, so);
                    t = __fsub_rn(qo.y, xv.y); so = __fmaf_rn(t, t, so);
                    t = __fsub_rn(qo.z, xv.z); so = __fmaf_rn(t, t, so);
                    t = __fsub_rn(qo.w, xv.w); so = __fmaf_rn(t, t, so);
                    t = __fsub_rn(qn.x, xv.x); sn = __fmaf_rn(t, t, sn);
                    o.x = __fadd_rn(xv.x, t);
                    t = __fsub_rn(qn.y, xv.y); sn = __fmaf_rn(t, t, sn);
                    o.y = __fadd_rn(xv.y, t);
                    t = __fsub_rn(qn.z, xv.z); sn = __fmaf_rn(t, t, sn);
                    o.z = __fadd_rn(xv.z, t);
                    t = __fsub_rn(qn.w, xv.w); sn = __fmaf_rn(t, t, sn);
                    o.w = __fadd_rn(xv.w, t);
                    *reinterpret_cast<float4*>(out + (size_t)row * D + d0) = o;
                    part = sn - so;  // exactly 0 when bi == fidx
                }
#pragma unroll
                for (int off = 32; off > 0; off >>= 1)
                    part += __shfl_down(part, off, 64);
                if (lane == 0 && part != 0.f) atomicAdd(loss_acc, part);
            }
    }
}

__global__ void vq_finalize(const float* __restrict__ loss_acc,
                            float* __restrict__ out_loss) {
    if (threadIdx.x == 0) {
        float mm = loss_acc[0] / (float)NELEM;  // /2^23: exact
        out_loss[0] = 1.25f * mm;               // == fl(0.25m + m)
    }
}

extern "C" void kernel_launch(void* const* d_in, const int* in_sizes, int n_in,
                              void* d_out, int out_size, void* d_ws, size_t ws_size,
                              hipStream_t stream) {
    const float* x = (const float*)d_in[0];
    const float* emb = (const float*)d_in[1];
    float* out = (float*)d_out;

    float* ws = (float*)d_ws;
    float* loss_acc = ws;
    int* cnt = (int*)ws + 1;
    float* e2 = ws + 64;
    unsigned short* ebf = (unsigned short*)(ws + 1024);  // 128 KB
    float* embT = ws + 33792;                            // 128 KB
    int* slow = (int*)(ws + 66560);                      // 64 KB

    vq_prep<<<8, 256, 0, stream>>>(emb, e2, ebf, embT, loss_acc, cnt);
    vq_main<<<NROWS / RPB, 256, 0, stream>>>(x, e2, ebf, embT, out, loss_acc,
                                             slow, cnt);
    vq_fix<<<512, 256, 0, stream>>>(x, emb, embT, e2, slow, cnt, out, loss_acc);
    vq_finalize<<<1, 64, 0, stream>>>(loss_acc, out + NELEM);
}

// Round 2
// 158.753 us; speedup vs baseline: 1.1878x; 1.1878x over previous
//
#include <hip/hip_runtime.h>

// VQ-VAE vector quantization forward — MFMA fast-path + exact np recheck.
// x: [32,64,64,64] f32 -> flat [N=131072, D=64]; embeddings: [D=64, K=512].
//
// Exactness contract (validated rounds 2-11 at absmax 0.0): chosen index per
// row == np argmin over dist_k = fl(fl(A+B_k) - fl(2*sim_k)), first-min tie;
// A = np pairwise 8-acc sum(f*f); B_k = sequential sum(e*e); sim = sequential
// FMA chain over d. out = fl(x + fl(q-x)); loss = 1.25*mean((q-x)^2).
//
// Round 12 — r11 books: all top-5 dispatches are vq_fix @61.5us, VGPR=80
// (acc[8][8] spilled), ~0% VALU -> latency-poisoned. vq_main/prep both <61.
//  - vq_fix REWRITE: 4 rows/wave, x rows register-resident via ONE coalesced
//    vector load each + shuffle broadcast (kills 1024 serial scalar loads +
//    the spill; acc[4][8]=32 regs). A via distributed pairwise-8 xor-tree
//    (bit-exact: fadd commutes bitwise, grouping identical to np). ev loads
//    amortized x4. Grid 512x256.
//  - vq_main: triple-buffered sbf + lgkmcnt(0)-only raw barrier per t (the
//    __syncthreads vmcnt(0) drain stalled on the same-iter staged load).
//    Staged load now targets t+2 -> a full iteration of latency slack.
//  - vq_prep: 32 blocks (1 per ebf tile), byte-identical outputs, ~4x CUs.
// finalize / margin logic / layouts: byte-identical to r11.

constexpr int D = 64;
constexpr int K = 512;
constexpr int NROWS = 131072;
constexpr long long NELEM = 8388608LL;
constexpr int RPB = 128;     // rows per block (2 row-tiles per wave)
constexpr float THRESH = 1e-3f;
constexpr int SLOWCAP = 16384;

typedef __attribute__((ext_vector_type(8))) short bf16x8;
typedef __attribute__((ext_vector_type(4))) float f32x4;

__device__ __forceinline__ unsigned short bf16_rne(float f) {
    unsigned int u = __float_as_uint(f);
    unsigned int r = u + 0x7fffu + ((u >> 16) & 1u);
    return (unsigned short)(r >> 16);
}
__device__ __forceinline__ float bf16_f(unsigned short h) {
    return __uint_as_float(((unsigned int)h) << 16);
}

// ws map (float offsets): 0 loss | 1 cnt | 64 e2[512] | 1024 ebf (128KB)
// | 33792 embT[512*64] | 66560 slow[16384] ints.

// Prep: 32 blocks x 256. Block b owns ebf tile b = codes [b*16, b*16+16).
// Outputs byte-identical to the r10/r11 8-block version.
__global__ __launch_bounds__(256) void vq_prep(const float* __restrict__ emb,
                                               float* __restrict__ e2,
                                               unsigned short* __restrict__ ebf,
                                               float* __restrict__ embT,
                                               float* __restrict__ loss_acc,
                                               int* __restrict__ cnt) {
    const int tid = threadIdx.x;
    const int b = blockIdx.x;
    const int c0 = b * 16;
    __shared__ float se[64][17];  // se[d][cl], padded

    // Stage 64 d x 16 codes (64B segments, 4 independent loads/thread).
#pragma unroll
    for (int it = 0; it < 4; ++it) {
        const int idx = it * 256 + tid;   // 0..1023
        const int d = idx >> 4, cl = idx & 15;
        se[d][cl] = emb[d * K + c0 + cl];
    }
    __syncthreads();

    // e2: np axis-0 sequential order (identical rounding chain).
    if (tid < 16) {
        const int cl = tid;
        float bacc = __fmul_rn(se[0][cl], se[0][cl]);
#pragma unroll
        for (int d = 1; d < 64; ++d)
            bacc = __fadd_rn(bacc, __fmul_rn(se[d][cl], se[d][cl]));
        e2[c0 + cl] = bacc;
    }

    // embT[c][d]: 256 float4, one per thread.
    {
        const int cl = tid >> 4;
        const int d0 = (tid & 15) * 4;
        float4 v;
        v.x = se[d0 + 0][cl];
        v.y = se[d0 + 1][cl];
        v.z = se[d0 + 2][cl];
        v.w = se[d0 + 3][cl];
        *reinterpret_cast<float4*>(embT + (size_t)(c0 + cl) * D + d0) = v;
    }

    // ebf tile b: 256 uint4, one per thread. Layout (r9-identical):
    // tile*2048 + table*1024 + half*512 + lane*8 + j,
    // value = split_table( e[d = q*8+j+32*half][c = tile*16 + (lane&15)] ).
    {
        const int table = tid >> 7;
        const int half = (tid >> 6) & 1;
        const int lane = tid & 63;
        const int q = lane >> 4, mm = lane & 15;
        unsigned short v[8];
#pragma unroll
        for (int j = 0; j < 8; ++j) {
            const float e = se[q * 8 + j + 32 * half][mm];
            unsigned short h1 = bf16_rne(e);
            v[j] = table ? bf16_rne(e - bf16_f(h1)) : h1;
        }
        *reinterpret_cast<uint4*>(ebf + (size_t)b * 2048 + table * 1024 +
                                  half * 512 + lane * 8) =
            *reinterpret_cast<const uint4*>(&v[0]);
    }

    if (b == 0 && tid == 0) { loss_acc[0] = 0.f; cnt[0] = 0; }
}

// Main: MFMA argmin, 2 row-tiles/wave, triple-buffered LDS ebf staging with
// lgkm-only barriers (no per-t vmcnt drain) + fused epilogue + loss.
__global__ __launch_bounds__(256, 4) void vq_main(
    const float* __restrict__ x, const float* __restrict__ e2g,
    const unsigned short* __restrict__ ebf, const float* __restrict__ embT,
    float* __restrict__ out, float* __restrict__ loss_acc,
    int* __restrict__ slow, int* __restrict__ cnt) {
    const int tid = threadIdx.x;
    const int l = tid & 63;
    const int wv = tid >> 6;
    const int m = l & 15, q = l >> 4;

    __shared__ __align__(16) unsigned short sbf[3][2048];  // 3 x 4KB tile
    __shared__ float se2[512];
    __shared__ int bxl[RPB];
    __shared__ float wsum[4];

    // Prologue staging: tile 0 -> sbf[0], e2 -> se2.
    {
        uint4 s0 = *reinterpret_cast<const uint4*>(ebf + tid * 8);
        *reinterpret_cast<uint4*>(&sbf[0][tid * 8]) = s0;
        if (tid < 128)
            reinterpret_cast<float4*>(se2)[tid] =
                reinterpret_cast<const float4*>(e2g)[tid];
    }

    // A-fragments for 2 row-tiles (rows wv*32 + rt*16 + m).
    bf16x8 a10[2], a11[2], a20[2], a21[2];
#pragma unroll
    for (int rt = 0; rt < 2; ++rt) {
        const float* xr =
            x + ((size_t)blockIdx.x * RPB + wv * 32 + rt * 16 + m) * D + q * 8;
        float4 v0 = *reinterpret_cast<const float4*>(xr);
        float4 v1 = *reinterpret_cast<const float4*>(xr + 4);
        float4 v2 = *reinterpret_cast<const float4*>(xr + 32);
        float4 v3 = *reinterpret_cast<const float4*>(xr + 36);
        float h0[8] = {v0.x, v0.y, v0.z, v0.w, v1.x, v1.y, v1.z, v1.w};
        float h1f[8] = {v2.x, v2.y, v2.z, v2.w, v3.x, v3.y, v3.z, v3.w};
        union { bf16x8 v; unsigned short u[8]; } u10, u11, u20, u21;
#pragma unroll
        for (int j = 0; j < 8; ++j) {
            unsigned short p = bf16_rne(h0[j]), r = bf16_rne(h1f[j]);
            u10.u[j] = p; u11.u[j] = r;
            u20.u[j] = bf16_rne(h0[j] - bf16_f(p));
            u21.u[j] = bf16_rne(h1f[j] - bf16_f(r));
        }
        a10[rt] = u10.v; a11[rt] = u11.v; a20[rt] = u20.v; a21[rt] = u21.v;
    }

    float m1[2][4], m2[2][4];
    int i1[2][4];
#pragma unroll
    for (int rt = 0; rt < 2; ++rt)
#pragma unroll
        for (int g = 0; g < 4; ++g) {
            m1[rt][g] = 3.0e38f; m2[rt][g] = 3.0e38f; i1[rt][g] = 0;
        }

    // Stage tile 1 into regs; full barrier once (drains everything).
    uint4 stg = *reinterpret_cast<const uint4*>(ebf + 2048 + tid * 8);
    __syncthreads();

    // Per step T (read buf RB, write buf WB=(T+1)%3):
    //   ds_write stg (tile T+1)  [WB last read at T-2 -> safe]
    //   issue global load of tile T+2 into stg  [a full step of slack]
    //   ds_read b-frags from RB, 16 MFMAs, min-update
    //   s_waitcnt lgkmcnt(0); s_barrier   [vmcnt NOT drained in-loop]
#define VQ_STEP(T, RB, WB)                                                     \
    do {                                                                       \
        *reinterpret_cast<uint4*>(&sbf[WB][tid * 8]) = stg;                    \
        stg = *reinterpret_cast<const uint4*>(ebf + (((T) + 2) & 31) * 2048 +  \
                                              tid * 8);                        \
        const unsigned short* tb = &sbf[RB][l * 8];                            \
        bf16x8 b10 = *reinterpret_cast<const bf16x8*>(tb);                     \
        bf16x8 b11 = *reinterpret_cast<const bf16x8*>(tb + 512);               \
        bf16x8 b20 = *reinterpret_cast<const bf16x8*>(tb + 1024);              \
        bf16x8 b21 = *reinterpret_cast<const bf16x8*>(tb + 1536);              \
        const float Bn = se2[(T) * 16 + m];                                    \
        const int col = (T) * 16 + m;                                          \
        f32x4 cp[2], cq[2];                                                    \
        _Pragma("unroll") for (int rt = 0; rt < 2; ++rt) {                     \
            cp[rt] = f32x4{0.f, 0.f, 0.f, 0.f};                                \
            cq[rt] = f32x4{0.f, 0.f, 0.f, 0.f};                                \
        }                                                                      \
        _Pragma("unroll") for (int rt = 0; rt < 2; ++rt) {                     \
            cp[rt] = __builtin_amdgcn_mfma_f32_16x16x32_bf16(a10[rt], b10, cp[rt], 0, 0, 0); \
            cq[rt] = __builtin_amdgcn_mfma_f32_16x16x32_bf16(a20[rt], b10, cq[rt], 0, 0, 0); \
            cp[rt] = __builtin_amdgcn_mfma_f32_16x16x32_bf16(a11[rt], b11, cp[rt], 0, 0, 0); \
            cq[rt] = __builtin_amdgcn_mfma_f32_16x16x32_bf16(a21[rt], b11, cq[rt], 0, 0, 0); \
            cp[rt] = __builtin_amdgcn_mfma_f32_16x16x32_bf16(a20[rt], b20, cp[rt], 0, 0, 0); \
            cq[rt] = __builtin_amdgcn_mfma_f32_16x16x32_bf16(a10[rt], b20, cq[rt], 0, 0, 0); \
            cp[rt] = __builtin_amdgcn_mfma_f32_16x16x32_bf16(a21[rt], b21, cp[rt], 0, 0, 0); \
            cq[rt] = __builtin_amdgcn_mfma_f32_16x16x32_bf16(a11[rt], b21, cq[rt], 0, 0, 0); \
        }                                                                      \
        _Pragma("unroll") for (int rt = 0; rt < 2; ++rt)                       \
            _Pragma("unroll") for (int g = 0; g < 4; ++g) {                    \
                float s = fmaf(-2.f, cp[rt][g] + cq[rt][g], Bn);               \
                m2[rt][g] = fminf(fmaxf(s, m1[rt][g]), m2[rt][g]);             \
                bool lt1 = s < m1[rt][g];                                      \
                if (lt1) { m1[rt][g] = s; i1[rt][g] = col; }                   \
            }                                                                  \
        asm volatile("s_waitcnt lgkmcnt(0)" ::: "memory");                     \
        __builtin_amdgcn_s_barrier();                                          \
    } while (0)

#pragma unroll 1
    for (int t3 = 0; t3 < 30; t3 += 3) {
        VQ_STEP(t3, 0, 1);
        VQ_STEP(t3 + 1, 1, 2);
        VQ_STEP(t3 + 2, 2, 0);
    }
    VQ_STEP(30, 0, 1);
    VQ_STEP(31, 1, 2);
#undef VQ_STEP

    // Combine across the 16 lanes of each quad (validated rounds 7-9).
#pragma unroll
    for (int rt = 0; rt < 2; ++rt)
#pragma unroll
        for (int g = 0; g < 4; ++g) {
#pragma unroll
            for (int off = 1; off < 16; off <<= 1) {
                float o1 = __shfl_xor(m1[rt][g], off, 64);
                int oi = __shfl_xor(i1[rt][g], off, 64);
                float o2 = __shfl_xor(m2[rt][g], off, 64);
                float nm2 =
                    fminf(fmaxf(m1[rt][g], o1), fminf(m2[rt][g], o2));
                bool take = (o1 < m1[rt][g]) ||
                            (o1 == m1[rt][g] && oi < i1[rt][g]);
                if (take) { m1[rt][g] = o1; i1[rt][g] = oi; }
                m2[rt][g] = nm2;  // equal mins, diff idx -> gap 0 -> slow
            }
            if (m == 0) {
                const int rl = wv * 32 + rt * 16 + q * 4 + g;  // row in block
                bxl[rl] = i1[rt][g];
                if (!((m2[rt][g] - m1[rt][g]) > THRESH)) {
                    int p = atomicAdd(cnt, 1);
                    if (p < SLOWCAP)
                        slow[p] = ((blockIdx.x * RPB + rl) << 9) | i1[rt][g];
                }
            }
        }
    __syncthreads();

    // Fused epilogue (r6-validated numerics, embT contiguous gather).
    float lsum = 0.f;
#pragma unroll
    for (int j = 0; j < 8; ++j) {
        const int e4 = j * 256 + tid;
        const int rr2 = e4 >> 4;
        const int d0 = (e4 & 15) * 4;
        const size_t gbase = (size_t)(blockIdx.x * RPB + rr2) * D + d0;
        const float4 xv = *reinterpret_cast<const float4*>(x + gbase);
        const float4 qv =
            *reinterpret_cast<const float4*>(embT + bxl[rr2] * D + d0);
        float4 o;
        float t;
        t = __fsub_rn(qv.x, xv.x); lsum = __fmaf_rn(t, t, lsum);
        o.x = __fadd_rn(xv.x, t);
        t = __fsub_rn(qv.y, xv.y); lsum = __fmaf_rn(t, t, lsum);
        o.y = __fadd_rn(xv.y, t);
        t = __fsub_rn(qv.z, xv.z); lsum = __fmaf_rn(t, t, lsum);
        o.z = __fadd_rn(xv.z, t);
        t = __fsub_rn(qv.w, xv.w); lsum = __fmaf_rn(t, t, lsum);
        o.w = __fadd_rn(xv.w, t);
        *reinterpret_cast<float4*>(out + gbase) = o;
    }
#pragma unroll
    for (int off = 32; off > 0; off >>= 1) lsum += __shfl_down(lsum, off, 64);
    if (l == 0) wsum[wv] = lsum;
    __syncthreads();
    if (tid == 0)
        atomicAdd(loss_acc, wsum[0] + wsum[1] + wsum[2] + wsum[3]);
}

// Fix: exact np rescan of flagged rows. r12: 4 rows/wave, x rows register-
// resident (1 coalesced vector load per row + shuffle broadcast), A via
// distributed pairwise-8 xor-tree (bit-exact vs np grouping since fl(a+b)
// == fl(b+a)). acc[4][8]=32 regs -> no spill. ev loads amortized x4.
// All np-exact chains (sequential-d FMA, first-min tie, rewrite, loss delta)
// verbatim from r9/r10.
__global__ __launch_bounds__(256, 2) void vq_fix(const float* __restrict__ x,
                                                 const float* __restrict__ emb,
                                                 const float* __restrict__ embT,
                                                 const float* __restrict__ e2g,
                                                 const int* __restrict__ slow,
                                                 const int* __restrict__ cnt,
                                                 float* __restrict__ out,
                                                 float* __restrict__ loss_acc) {
    int n = cnt[0];
    if (n > SLOWCAP) n = SLOWCAP;
    const int lane = threadIdx.x & 63;
    const int wg = blockIdx.x * 4 + (threadIdx.x >> 6);  // 2048 waves
#pragma unroll 1
    for (int base = wg * 4; base < n; base += 2048 * 4) {
        const int c4 = (n - base < 4) ? (n - base) : 4;
        int rows[4], fidxs[4];
        float xr[4], A[4];
#pragma unroll
        for (int j = 0; j < 4; ++j) {
            const int src = base + ((j < c4) ? j : 0);  // pad with entry 0
            const int entry = __builtin_amdgcn_readfirstlane(slow[src]);
            rows[j] = entry >> 9;
            fidxs[j] = entry & 511;
            xr[j] = x[(size_t)rows[j] * D + lane];  // whole row in the wave
        }
        // A[j]: np pairwise-8. Lane group (lane&7)=jj computes chain r8[jj]
        // (ii ascending, np order); xor-tree 1/2/4 reproduces the exact
        // ((r0+r1)+(r2+r3))+((r4+r5)+(r6+r7)) grouping (fadd commutes
        // bitwise). Every lane ends holding A.
#pragma unroll
        for (int j = 0; j < 4; ++j) {
            const int jj = lane & 7;
            float v = __shfl(xr[j], jj, 64);
            float r8 = __fmul_rn(v, v);
#pragma unroll
            for (int ii = 8; ii < 64; ii += 8) {
                v = __shfl(xr[j], ii + jj, 64);
                r8 = __fadd_rn(r8, __fmul_rn(v, v));
            }
            r8 = __fadd_rn(r8, __shfl_xor(r8, 1, 64));
            r8 = __fadd_rn(r8, __shfl_xor(r8, 2, 64));
            r8 = __fadd_rn(r8, __shfl_xor(r8, 4, 64));
            A[j] = r8;
        }
        // Shared sim phase: one 2KB ev slice feeds 4 rows; xd via shuffle
        // broadcast (no scalar x loads). np-exact sequential-d FMA chains.
        float acc[4][8];
#pragma unroll
        for (int j = 0; j < 4; ++j)
#pragma unroll
            for (int u = 0; u < 8; ++u) acc[j][u] = 0.f;
#pragma unroll 4
        for (int d = 0; d < D; ++d) {
            float ev[8];
#pragma unroll
            for (int u = 0; u < 8; ++u) ev[u] = emb[d * K + lane + 64 * u];
#pragma unroll
            for (int j = 0; j < 4; ++j) {
                const float xd = __shfl(xr[j], d, 64);
#pragma unroll
                for (int u = 0; u < 8; ++u)
                    acc[j][u] = __fmaf_rn(xd, ev[u], acc[j][u]);
            }
        }
        float e2v[8];
#pragma unroll
        for (int u = 0; u < 8; ++u) e2v[u] = e2g[lane + 64 * u];
        // Per-row argmin + rewrite + loss delta (r9-identical chains).
#pragma unroll
        for (int j = 0; j < 4; ++j)
            if (j < c4) {
                const int row = rows[j];
                const int fidx = fidxs[j];
                float bv = 3.0e38f;
                int bi = 0;
#pragma unroll
                for (int u = 0; u < 8; ++u) {
                    const int c = lane + 64 * u;
                    float dv = __fsub_rn(__fadd_rn(A[j], e2v[u]),
                                         __fmul_rn(2.f, acc[j][u]));
                    if (dv < bv) { bv = dv; bi = c; }  // ascending c in lane
                }
#pragma unroll
                for (int off = 1; off < 64; off <<= 1) {
                    float ov = __shfl_xor(bv, off, 64);
                    int oi = __shfl_xor(bi, off, 64);
                    if (ov < bv || (ov == bv && oi < bi)) { bv = ov; bi = oi; }
                }
                float part = 0.f;
                if (lane < 16) {
                    const int d0 = lane * 4;
                    const float4 xv = *reinterpret_cast<const float4*>(
                        x + (size_t)row * D + d0);
                    const float4 qo = *reinterpret_cast<const float4*>(
                        embT + fidx * D + d0);
                    const float4 qn = *reinterpret_cast<const float4*>(
                        embT + bi * D + d0);
                    float so = 0.f, sn = 0.f, t;
                    float4 o;
                    t = __fsub_rn(qo.x, xv.x); so = __fmaf_rn(t, t, so);
                    t = __fsub_rn(qo.y, xv.y); so = __fmaf_rn(t, t, so);
                    t = __fsub_rn(qo.z, xv.z); so = __fmaf_rn(t, t, so);
                    t = __fsub_rn(qo.w, xv.w); so = __fmaf_rn(t, t, so);
                    t = __fsub_rn(qn.x, xv.x); sn = __fmaf_rn(t, t, sn);
                    o.x = __fadd_rn(xv.x, t);
                    t = __fsub_rn(qn.y, xv.y); sn = __fmaf_rn(t, t, sn);
                    o.y = __fadd_rn(xv.y, t);
                    t = __fsub_rn(qn.z, xv.z); sn = __fmaf_rn(t, t, sn);
                    o.z = __fadd_rn(xv.z, t);
                    t = __fsub_rn(qn.w, xv.w); sn = __fmaf_rn(t, t, sn);
                    o.w = __fadd_rn(xv.w, t);
                    *reinterpret_cast<float4*>(out + (size_t)row * D + d0) = o;
                    part = sn - so;  // exactly 0 when bi == fidx
                }
#pragma unroll
                for (int off = 32; off > 0; off >>= 1)
                    part += __shfl_down(part, off, 64);
                if (lane == 0 && part != 0.f) atomicAdd(loss_acc, part);
            }
    }
}

__global__ void vq_finalize(const float* __restrict__ loss_acc,
                            float* __restrict__ out_loss) {
    if (threadIdx.x == 0) {
        float mm = loss_acc[0] / (float)NELEM;  // /2^23: exact
        out_loss[0] = 1.25f * mm;               // == fl(0.25m + m)
    }
}

extern "C" void kernel_launch(void* const* d_in, const int* in_sizes, int n_in,
                              void* d_out, int out_size, void* d_ws, size_t ws_size,
                              hipStream_t stream) {
    const float* x = (const float*)d_in[0];
    const float* emb = (const float*)d_in[1];
    float* out = (float*)d_out;

    float* ws = (float*)d_ws;
    float* loss_acc = ws;
    int* cnt = (int*)ws + 1;
    float* e2 = ws + 64;
    unsigned short* ebf = (unsigned short*)(ws + 1024);  // 128 KB
    float* embT = ws + 33792;                            // 128 KB
    int* slow = (int*)(ws + 66560);                      // 64 KB

    vq_prep<<<32, 256, 0, stream>>>(emb, e2, ebf, embT, loss_acc, cnt);
    vq_main<<<NROWS / RPB, 256, 0, stream>>>(x, e2, ebf, embT, out, loss_acc,
                                             slow, cnt);
    vq_fix<<<512, 256, 0, stream>>>(x, emb, embT, e2, slow, cnt, out, loss_acc);
    vq_finalize<<<1, 64, 0, stream>>>(loss_acc, out + NELEM);
}